// Round 1
// baseline (1879.613 us; speedup 1.0000x reference)
//
#include <hip/hip_runtime.h>
#include <hip/hip_bf16.h>

// ---------------------------------------------------------------------------
// GNN: hiddens = relu(gcn(x,W1,b1)); emb = gcn(hiddens,W2,b2);
// preds[e,h] = <emb[qr,h,:], emb[qc,h,:]>; pred_i/j = preds[., y[qr/qc]]
// Strategy: build CSR-by-dst once (count -> scan -> fill, with per-edge norm),
// dense fp32 GEMMs with W in LDS, gather-based aggregation (no feature atomics),
// wave-per-edge query scoring with shuffle reduction.
// ---------------------------------------------------------------------------

__global__ void count_kernel(const int* __restrict__ dst, int* __restrict__ cnt, int E) {
    int e = blockIdx.x * blockDim.x + threadIdx.x;
    if (e < E) atomicAdd(&cnt[dst[e]], 1);
}

__global__ __launch_bounds__(1024) void scan_kernel(const int* __restrict__ cnt,
                                                    int* __restrict__ row_ptr,
                                                    int* __restrict__ cursor,
                                                    float* __restrict__ dinv,
                                                    int n, int E) {
    __shared__ int sums[1024];
    int t = threadIdx.x;
    int chunk = (n + 1023) / 1024;
    int lo = t * chunk;
    int hi = lo + chunk; if (hi > n) hi = n; if (lo > n) lo = n;
    int s = 0;
    for (int i = lo; i < hi; ++i) s += cnt[i];
    sums[t] = s;
    __syncthreads();
    // Hillis-Steele inclusive scan over 1024 thread sums
    for (int off = 1; off < 1024; off <<= 1) {
        int v = (t >= off) ? sums[t - off] : 0;
        __syncthreads();
        sums[t] += v;
        __syncthreads();
    }
    int run = (t == 0) ? 0 : sums[t - 1];
    for (int i = lo; i < hi; ++i) {
        row_ptr[i] = run;
        cursor[i]  = run;
        int c = cnt[i];
        dinv[i] = rsqrtf((float)(c + 1));  // +1 self-loop
        run += c;
    }
    if (t == 0) row_ptr[n] = E;
}

__global__ void fill_kernel(const int* __restrict__ src, const int* __restrict__ dst,
                            int* __restrict__ cursor, const float* __restrict__ dinv,
                            int* __restrict__ csr_src, float* __restrict__ csr_wt, int E) {
    int e = blockIdx.x * blockDim.x + threadIdx.x;
    if (e < E) {
        int s = src[e], d = dst[e];
        int pos = atomicAdd(&cursor[d], 1);
        csr_src[pos] = s;
        csr_wt[pos]  = dinv[s] * dinv[d];
    }
}

// C[N, ldw-chunk] = X[N,128] @ W[128, ldw], one 128-col chunk per blockIdx.y.
__global__ __launch_bounds__(256) void gemm_rm(const float* __restrict__ X,
                                               const float* __restrict__ W,
                                               float* __restrict__ C,
                                               int N, int ldw) {
    __shared__ float Wl[128 * 128];  // 64 KB
    __shared__ float Xl[32 * 128];   // 16 KB
    int tx = threadIdx.x & 31;       // col group of 4 (covers 128 cols)
    int ty = threadIdx.x >> 5;       // 0..7 (row within group of 8)
    int colOff = blockIdx.y * 128;
    int row0 = blockIdx.x * 32;

    for (int i = threadIdx.x; i < 128 * 32; i += 256) {   // 4096 float4 of W chunk
        int k = i >> 5, j4 = i & 31;
        ((float4*)Wl)[i] = *(const float4*)(W + (size_t)k * ldw + colOff + j4 * 4);
    }
    for (int i = threadIdx.x; i < 32 * 32; i += 256) {    // 1024 float4 of X tile
        int r = i >> 5, k4 = i & 31;
        int row = row0 + r; if (row >= N) row = N - 1;
        ((float4*)Xl)[i] = *(const float4*)(X + (size_t)row * 128 + k4 * 4);
    }
    __syncthreads();

    float4 acc[4] = {};
    for (int k = 0; k < 128; ++k) {
        float4 w = ((const float4*)Wl)[k * 32 + tx];
#pragma unroll
        for (int i = 0; i < 4; ++i) {
            float xv = Xl[(ty + 8 * i) * 128 + k];
            acc[i].x += xv * w.x; acc[i].y += xv * w.y;
            acc[i].z += xv * w.z; acc[i].w += xv * w.w;
        }
    }
#pragma unroll
    for (int i = 0; i < 4; ++i) {
        int r = row0 + ty + 8 * i;
        if (r < N)
            *(float4*)(C + (size_t)r * ldw + colOff + tx * 4) = acc[i];
    }
}

// layer-1 aggregation (128 feats), one node per 128-thread block, + bias + relu
__global__ __launch_bounds__(128) void agg1_kernel(const float* __restrict__ h1,
                                                   const float* __restrict__ b1,
                                                   const int* __restrict__ row_ptr,
                                                   const int* __restrict__ csr_src,
                                                   const float* __restrict__ csr_wt,
                                                   const float* __restrict__ dinv,
                                                   float* __restrict__ hiddens, int n) {
    int node = blockIdx.x;
    int f = threadIdx.x;
    float di = dinv[node];
    float acc = h1[(size_t)node * 128 + f] * di * di;   // self-loop
    int e0 = row_ptr[node], e1 = row_ptr[node + 1];
    for (int e = e0; e < e1; ++e) {
        int s = csr_src[e];
        float w = csr_wt[e];
        acc += h1[(size_t)s * 128 + f] * w;
    }
    acc += b1[f];
    hiddens[(size_t)node * 128 + f] = acc > 0.f ? acc : 0.f;
}

// layer-2 aggregation (512 feats as 128 float4), one node per 128-thread block, + bias
__global__ __launch_bounds__(128) void agg2_kernel(const float* __restrict__ h2,
                                                   const float* __restrict__ b2,
                                                   const int* __restrict__ row_ptr,
                                                   const int* __restrict__ csr_src,
                                                   const float* __restrict__ csr_wt,
                                                   const float* __restrict__ dinv,
                                                   float* __restrict__ emb, int n) {
    int node = blockIdx.x;
    int f4 = threadIdx.x;  // float4 index, 0..127
    float di = dinv[node];
    const float4* h2v = (const float4*)h2;
    float4 v = h2v[(size_t)node * 128 + f4];
    float sl = di * di;
    float4 acc = { v.x * sl, v.y * sl, v.z * sl, v.w * sl };
    int e0 = row_ptr[node], e1 = row_ptr[node + 1];
    for (int e = e0; e < e1; ++e) {
        int s = csr_src[e];
        float w = csr_wt[e];
        float4 u = h2v[(size_t)s * 128 + f4];
        acc.x += u.x * w; acc.y += u.y * w; acc.z += u.z * w; acc.w += u.w * w;
    }
    float4 bb = ((const float4*)b2)[f4];
    acc.x += bb.x; acc.y += bb.y; acc.z += bb.z; acc.w += bb.w;
    ((float4*)emb)[(size_t)node * 128 + f4] = acc;
}

// one wave per query edge: 8-head dot products + head select
__global__ __launch_bounds__(256) void query_kernel(const float* __restrict__ emb,
                                                    const int* __restrict__ qrow,
                                                    const int* __restrict__ qcol,
                                                    const int* __restrict__ y,
                                                    float* __restrict__ pred_i,
                                                    float* __restrict__ pred_j,
                                                    float* __restrict__ pred, int Q) {
    int wave = (int)((blockIdx.x * 256 + threadIdx.x) >> 6);
    int lane = threadIdx.x & 63;
    if (wave >= Q) return;
    int r = qrow[wave], c = qcol[wave];
    const float* er = emb + (size_t)r * 512;
    const float* ec = emb + (size_t)c * 512;
    float p[8];
#pragma unroll
    for (int h = 0; h < 8; ++h) p[h] = er[h * 64 + lane] * ec[h * 64 + lane];
#pragma unroll
    for (int off = 32; off >= 1; off >>= 1) {
#pragma unroll
        for (int h = 0; h < 8; ++h) p[h] += __shfl_xor(p[h], off, 64);
    }
    if (lane == 0) {
        int yi = y[r], yj = y[c];
        float pi = p[0], pj = p[0];
#pragma unroll
        for (int h = 1; h < 8; ++h) {
            pi = (yi == h) ? p[h] : pi;
            pj = (yj == h) ? p[h] : pj;
        }
        pred_i[wave] = pi;
        pred_j[wave] = pj;
        pred[wave]   = 0.5f * (pi + pj);
    }
}

extern "C" void kernel_launch(void* const* d_in, const int* in_sizes, int n_in,
                              void* d_out, int out_size, void* d_ws, size_t ws_size,
                              hipStream_t stream) {
    const float* x   = (const float*)d_in[0];
    const float* W1  = (const float*)d_in[1];
    const float* b1  = (const float*)d_in[2];
    const float* W2  = (const float*)d_in[3];
    const float* b2  = (const float*)d_in[4];
    const int* edge  = (const int*)d_in[5];
    const int* qedge = (const int*)d_in[6];
    const int* y     = (const int*)d_in[7];

    const int N = in_sizes[0] / 128;   // 100000
    const int E = in_sizes[5] / 2;     // 1600000
    const int Q = in_sizes[6] / 2;     // 400000

    float* out     = (float*)d_out;
    float* hiddens = out;                         // [N,128]
    float* emb     = out + (size_t)N * 128;       // [N,512]
    float* pred_i  = emb + (size_t)N * 512;       // [Q]
    float* pred_j  = pred_i + Q;                  // [Q]
    float* pred    = pred_j + Q;                  // [Q]

    // workspace carve (256B aligned)
    char* w = (char*)d_ws;
    auto alloc = [&](size_t bytes) { char* p = w; w += (bytes + 255) & ~(size_t)255; return p; };
    int*   cnt     = (int*)alloc((size_t)N * 4);
    int*   row_ptr = (int*)alloc((size_t)(N + 1) * 4);
    int*   cursor  = (int*)alloc((size_t)N * 4);
    float* dinv    = (float*)alloc((size_t)N * 4);
    int*   csr_src = (int*)alloc((size_t)E * 4);
    float* csr_wt  = (float*)alloc((size_t)E * 4);
    float* h2      = (float*)alloc((size_t)N * 512 * 4);  // 204.8 MB
    // h1 staged in d_out's emb region ([N,512] >= [N,128]); overwritten by agg2 later
    float* h1 = emb;

    const int* esrc = edge;         const int* edst = edge + E;
    const int* qrow = qedge;        const int* qcol = qedge + Q;

    hipMemsetAsync(cnt, 0, (size_t)N * 4, stream);
    count_kernel<<<dim3((E + 255) / 256), dim3(256), 0, stream>>>(edst, cnt, E);
    scan_kernel<<<dim3(1), dim3(1024), 0, stream>>>(cnt, row_ptr, cursor, dinv, N, E);
    fill_kernel<<<dim3((E + 255) / 256), dim3(256), 0, stream>>>(esrc, edst, cursor, dinv, csr_src, csr_wt, E);

    gemm_rm<<<dim3((N + 31) / 32, 1), dim3(256), 0, stream>>>(x, W1, h1, N, 128);
    agg1_kernel<<<dim3(N), dim3(128), 0, stream>>>(h1, b1, row_ptr, csr_src, csr_wt, dinv, hiddens, N);
    gemm_rm<<<dim3((N + 31) / 32, 4), dim3(256), 0, stream>>>(hiddens, W2, h2, N, 512);
    agg2_kernel<<<dim3(N), dim3(128), 0, stream>>>(h2, b2, row_ptr, csr_src, csr_wt, dinv, emb, N);
    query_kernel<<<dim3((Q + 3) / 4), dim3(256), 0, stream>>>(emb, qrow, qcol, y, pred_i, pred_j, pred, Q);
}

// Round 2
// 1343.007 us; speedup vs baseline: 1.3996x; 1.3996x over previous
//
#include <hip/hip_runtime.h>
#include <hip/hip_bf16.h>

// ---------------------------------------------------------------------------
// GNN: hiddens = relu(gcn(x,W1,b1)); emb = gcn(hiddens,W2,b2);
// pred_i/j = <emb[r,y,:],emb[c,y,:]> at head y[r]/y[c].
//
// Key identity: A_norm @ (H @ W) = (A_norm @ H) @ W  — aggregate FIRST on the
// 128-feature input (512 B/edge gather, 51 MB working set), then dense GEMM
// with fused bias(+relu). Avoids ever materializing / gathering the 205 MB
// [N,512] pre-aggregation tensor (was 1.9 GB HBM per agg2 dispatch).
// Query kernel loads only the two selected heads (1 KB/edge, not 4 KB).
// ---------------------------------------------------------------------------

__global__ void count_kernel(const int* __restrict__ dst, int* __restrict__ cnt, int E) {
    int e = blockIdx.x * blockDim.x + threadIdx.x;
    if (e < E) atomicAdd(&cnt[dst[e]], 1);
}

__global__ __launch_bounds__(1024) void scan_kernel(const int* __restrict__ cnt,
                                                    int* __restrict__ row_ptr,
                                                    int* __restrict__ cursor,
                                                    float* __restrict__ dinv,
                                                    int n, int E) {
    __shared__ int sums[1024];
    int t = threadIdx.x;
    int chunk = (n + 1023) / 1024;
    int lo = t * chunk;
    int hi = lo + chunk; if (hi > n) hi = n; if (lo > n) lo = n;
    int s = 0;
    for (int i = lo; i < hi; ++i) s += cnt[i];
    sums[t] = s;
    __syncthreads();
    for (int off = 1; off < 1024; off <<= 1) {
        int v = (t >= off) ? sums[t - off] : 0;
        __syncthreads();
        sums[t] += v;
        __syncthreads();
    }
    int run = (t == 0) ? 0 : sums[t - 1];
    for (int i = lo; i < hi; ++i) {
        row_ptr[i] = run;
        cursor[i]  = run;
        int c = cnt[i];
        dinv[i] = rsqrtf((float)(c + 1));  // +1 self-loop
        run += c;
    }
    if (t == 0) row_ptr[n] = E;
}

__global__ void fill_kernel(const int* __restrict__ src, const int* __restrict__ dst,
                            int* __restrict__ cursor, const float* __restrict__ dinv,
                            int* __restrict__ csr_src, float* __restrict__ csr_wt, int E) {
    int e = blockIdx.x * blockDim.x + threadIdx.x;
    if (e < E) {
        int s = src[e], d = dst[e];
        int pos = atomicAdd(&cursor[d], 1);
        csr_src[pos] = s;
        csr_wt[pos]  = dinv[s] * dinv[d];
    }
}

// out[node,f] = dinv[node]^2 * feat[node,f] + sum_e csr_wt[e]*feat[csr_src[e],f]
// One node per 128-thread block; gather loop unrolled x4 for MLP (mean deg 16).
__global__ __launch_bounds__(128) void agg_kernel(const float* __restrict__ feat,
                                                  const int* __restrict__ row_ptr,
                                                  const int* __restrict__ csr_src,
                                                  const float* __restrict__ csr_wt,
                                                  const float* __restrict__ dinv,
                                                  float* __restrict__ out, int n) {
    int node = blockIdx.x;
    int f = threadIdx.x;
    float di = dinv[node];
    float acc = feat[(size_t)node * 128 + f] * di * di;   // self-loop
    int e0 = row_ptr[node], e1 = row_ptr[node + 1];
    int e = e0;
    for (; e + 4 <= e1; e += 4) {
        int s0 = csr_src[e],   s1 = csr_src[e+1], s2 = csr_src[e+2], s3 = csr_src[e+3];
        float w0 = csr_wt[e],  w1 = csr_wt[e+1],  w2 = csr_wt[e+2],  w3 = csr_wt[e+3];
        float v0 = feat[(size_t)s0 * 128 + f];
        float v1 = feat[(size_t)s1 * 128 + f];
        float v2 = feat[(size_t)s2 * 128 + f];
        float v3 = feat[(size_t)s3 * 128 + f];
        acc += v0 * w0 + v1 * w1 + v2 * w2 + v3 * w3;
    }
    for (; e < e1; ++e)
        acc += feat[(size_t)csr_src[e] * 128 + f] * csr_wt[e];
    out[(size_t)node * 128 + f] = acc;
}

// C[N, 128-col chunk] = X[N,128] @ W[128, ldw] + bias, optional relu.
__global__ __launch_bounds__(256) void gemm_rm(const float* __restrict__ X,
                                               const float* __restrict__ W,
                                               const float* __restrict__ bias,
                                               float* __restrict__ C,
                                               int N, int ldw, int do_relu) {
    __shared__ float Wl[128 * 128];  // 64 KB
    __shared__ float Xl[32 * 128];   // 16 KB
    int tx = threadIdx.x & 31;       // col group of 4 (covers 128 cols)
    int ty = threadIdx.x >> 5;       // 0..7 (row within group of 8)
    int colOff = blockIdx.y * 128;
    int row0 = blockIdx.x * 32;

    for (int i = threadIdx.x; i < 128 * 32; i += 256) {   // W chunk as float4
        int k = i >> 5, j4 = i & 31;
        ((float4*)Wl)[i] = *(const float4*)(W + (size_t)k * ldw + colOff + j4 * 4);
    }
    for (int i = threadIdx.x; i < 32 * 32; i += 256) {    // X tile as float4
        int r = i >> 5, k4 = i & 31;
        int row = row0 + r; if (row >= N) row = N - 1;
        ((float4*)Xl)[i] = *(const float4*)(X + (size_t)row * 128 + k4 * 4);
    }
    __syncthreads();

    float4 acc[4] = {};
    for (int k = 0; k < 128; ++k) {
        float4 w = ((const float4*)Wl)[k * 32 + tx];
#pragma unroll
        for (int i = 0; i < 4; ++i) {
            float xv = Xl[(ty + 8 * i) * 128 + k];
            acc[i].x += xv * w.x; acc[i].y += xv * w.y;
            acc[i].z += xv * w.z; acc[i].w += xv * w.w;
        }
    }
    float4 bb = *(const float4*)(bias + colOff + tx * 4);
#pragma unroll
    for (int i = 0; i < 4; ++i) {
        acc[i].x += bb.x; acc[i].y += bb.y; acc[i].z += bb.z; acc[i].w += bb.w;
        if (do_relu) {
            acc[i].x = acc[i].x > 0.f ? acc[i].x : 0.f;
            acc[i].y = acc[i].y > 0.f ? acc[i].y : 0.f;
            acc[i].z = acc[i].z > 0.f ? acc[i].z : 0.f;
            acc[i].w = acc[i].w > 0.f ? acc[i].w : 0.f;
        }
        int r = row0 + ty + 8 * i;
        if (r < N)
            *(float4*)(C + (size_t)r * ldw + colOff + tx * 4) = acc[i];
    }
}

// one 64-lane wave per query edge; load only the two selected heads (1 KB/edge)
__global__ __launch_bounds__(256) void query_kernel(const float* __restrict__ emb,
                                                    const int* __restrict__ qrow,
                                                    const int* __restrict__ qcol,
                                                    const int* __restrict__ y,
                                                    float* __restrict__ pred_i,
                                                    float* __restrict__ pred_j,
                                                    float* __restrict__ pred, int Q) {
    int wave = (int)((blockIdx.x * 256 + threadIdx.x) >> 6);
    int lane = threadIdx.x & 63;
    if (wave >= Q) return;
    int r = qrow[wave], c = qcol[wave];
    int yi = y[r], yj = y[c];   // same-address across wave -> broadcast
    const float* er = emb + (size_t)r * 512;
    const float* ec = emb + (size_t)c * 512;
    float pi = er[yi * 64 + lane] * ec[yi * 64 + lane];
    float pj = er[yj * 64 + lane] * ec[yj * 64 + lane];
#pragma unroll
    for (int off = 32; off >= 1; off >>= 1) {
        pi += __shfl_xor(pi, off, 64);
        pj += __shfl_xor(pj, off, 64);
    }
    if (lane == 0) {
        pred_i[wave] = pi;
        pred_j[wave] = pj;
        pred[wave]   = 0.5f * (pi + pj);
    }
}

extern "C" void kernel_launch(void* const* d_in, const int* in_sizes, int n_in,
                              void* d_out, int out_size, void* d_ws, size_t ws_size,
                              hipStream_t stream) {
    const float* x   = (const float*)d_in[0];
    const float* W1  = (const float*)d_in[1];
    const float* b1  = (const float*)d_in[2];
    const float* W2  = (const float*)d_in[3];
    const float* b2  = (const float*)d_in[4];
    const int* edge  = (const int*)d_in[5];
    const int* qedge = (const int*)d_in[6];
    const int* y     = (const int*)d_in[7];

    const int N = in_sizes[0] / 128;   // 100000
    const int E = in_sizes[5] / 2;     // 1600000
    const int Q = in_sizes[6] / 2;     // 400000

    float* out     = (float*)d_out;
    float* hiddens = out;                         // [N,128]
    float* emb     = out + (size_t)N * 128;       // [N,512]
    float* pred_i  = emb + (size_t)N * 512;       // [Q]
    float* pred_j  = pred_i + Q;                  // [Q]
    float* pred    = pred_j + Q;                  // [Q]

    // workspace carve (256B aligned)
    char* w = (char*)d_ws;
    auto alloc = [&](size_t bytes) { char* p = w; w += (bytes + 255) & ~(size_t)255; return p; };
    int*   cnt     = (int*)alloc((size_t)N * 4);
    int*   row_ptr = (int*)alloc((size_t)(N + 1) * 4);
    int*   cursor  = (int*)alloc((size_t)N * 4);
    float* dinv    = (float*)alloc((size_t)N * 4);
    int*   csr_src = (int*)alloc((size_t)E * 4);
    float* csr_wt  = (float*)alloc((size_t)E * 4);
    float* aggbuf  = (float*)alloc((size_t)N * 128 * 4);  // 51.2 MB, reused by both layers

    const int* esrc = edge;         const int* edst = edge + E;
    const int* qrow = qedge;        const int* qcol = qedge + Q;

    hipMemsetAsync(cnt, 0, (size_t)N * 4, stream);
    count_kernel<<<dim3((E + 255) / 256), dim3(256), 0, stream>>>(edst, cnt, E);
    scan_kernel<<<dim3(1), dim3(1024), 0, stream>>>(cnt, row_ptr, cursor, dinv, N, E);
    fill_kernel<<<dim3((E + 255) / 256), dim3(256), 0, stream>>>(esrc, edst, cursor, dinv, csr_src, csr_wt, E);

    // layer 1: aggregate x, then GEMM with fused bias+relu
    agg_kernel<<<dim3(N), dim3(128), 0, stream>>>(x, row_ptr, csr_src, csr_wt, dinv, aggbuf, N);
    gemm_rm<<<dim3((N + 31) / 32, 1), dim3(256), 0, stream>>>(aggbuf, W1, b1, hiddens, N, 128, 1);

    // layer 2: aggregate hiddens, then GEMM with fused bias
    agg_kernel<<<dim3(N), dim3(128), 0, stream>>>(hiddens, row_ptr, csr_src, csr_wt, dinv, aggbuf, N);
    gemm_rm<<<dim3((N + 31) / 32, 4), dim3(256), 0, stream>>>(aggbuf, W2, b2, emb, N, 512, 0);

    query_kernel<<<dim3((Q + 3) / 4), dim3(256), 0, stream>>>(emb, qrow, qcol, y, pred_i, pred_j, pred, Q);
}

// Round 3
// 1068.945 us; speedup vs baseline: 1.7584x; 1.2564x over previous
//
#include <hip/hip_runtime.h>
#include <hip/hip_bf16.h>

// ---------------------------------------------------------------------------
// GNN: hiddens = relu(gcn(x,W1,b1)); emb = gcn(hiddens,W2,b2);
// pred_i/j = <emb[r,y,:],emb[c,y,:]> at head y[r]/y[c].
//
// aggregate-then-transform: A_norm @ (H @ W) = (A_norm @ H) @ W.
// CSR build: count -> 3-phase parallel scan (196 blocks, was 280us on 1 CU)
// -> atomic fill with per-edge norm.
// ---------------------------------------------------------------------------

#define SCAN_SEG 512   // elements per scan block (256 threads x 2)

__global__ void count_kernel(const int* __restrict__ dst, int* __restrict__ cnt, int E) {
    int e = blockIdx.x * blockDim.x + threadIdx.x;
    if (e < E) atomicAdd(&cnt[dst[e]], 1);
}

// phase 1: per-block segment sums (coalesced)
__global__ __launch_bounds__(256) void blocksum_kernel(const int* __restrict__ cnt,
                                                       int* __restrict__ blocksum, int n) {
    __shared__ int red[4];
    int b = blockIdx.x, t = threadIdx.x;
    int i0 = b * SCAN_SEG + t;
    int s = 0;
    if (i0 < n) s += cnt[i0];
    if (i0 + 256 < n) s += cnt[i0 + 256];
#pragma unroll
    for (int off = 32; off >= 1; off >>= 1) s += __shfl_xor(s, off, 64);
    if ((t & 63) == 0) red[t >> 6] = s;
    __syncthreads();
    if (t == 0) blocksum[b] = red[0] + red[1] + red[2] + red[3];
}

// phase 2: exclusive scan of <=256 block sums in one small block
__global__ __launch_bounds__(256) void blockscan_kernel(const int* __restrict__ blocksum,
                                                        int* __restrict__ blockoff, int nb,
                                                        int* __restrict__ row_ptr, int n, int E) {
    __shared__ int s[256];
    int t = threadIdx.x;
    int v = (t < nb) ? blocksum[t] : 0;
    s[t] = v;
    __syncthreads();
    for (int off = 1; off < 256; off <<= 1) {
        int u = (t >= off) ? s[t - off] : 0;
        __syncthreads();
        s[t] += u;
        __syncthreads();
    }
    if (t < nb) blockoff[t] = s[t] - v;   // exclusive
    if (t == 0) row_ptr[n] = E;
}

// phase 3: per-block exclusive scan over its 512-elem segment -> row_ptr/cursor/dinv
__global__ __launch_bounds__(256) void csr_ptr_kernel(const int* __restrict__ cnt,
                                                      const int* __restrict__ blockoff,
                                                      int* __restrict__ row_ptr,
                                                      int* __restrict__ cursor,
                                                      float* __restrict__ dinv, int n) {
    __shared__ int s[256];
    int b = blockIdx.x, t = threadIdx.x;
    int i0 = b * SCAN_SEG + 2 * t;       // thread handles i0, i0+1
    int c0 = (i0     < n) ? cnt[i0]     : 0;
    int c1 = (i0 + 1 < n) ? cnt[i0 + 1] : 0;
    int pair = c0 + c1;
    s[t] = pair;
    __syncthreads();
    for (int off = 1; off < 256; off <<= 1) {
        int u = (t >= off) ? s[t - off] : 0;
        __syncthreads();
        s[t] += u;
        __syncthreads();
    }
    int excl = s[t] - pair + blockoff[b];
    if (i0 < n) {
        row_ptr[i0] = excl;
        cursor[i0]  = excl;
        dinv[i0]    = rsqrtf((float)(c0 + 1));
    }
    if (i0 + 1 < n) {
        row_ptr[i0 + 1] = excl + c0;
        cursor[i0 + 1]  = excl + c0;
        dinv[i0 + 1]    = rsqrtf((float)(c1 + 1));
    }
}

__global__ void fill_kernel(const int* __restrict__ src, const int* __restrict__ dst,
                            int* __restrict__ cursor, const float* __restrict__ dinv,
                            int* __restrict__ csr_src, float* __restrict__ csr_wt, int E) {
    int e = blockIdx.x * blockDim.x + threadIdx.x;
    if (e < E) {
        int s = src[e], d = dst[e];
        int pos = atomicAdd(&cursor[d], 1);
        csr_src[pos] = s;
        csr_wt[pos]  = dinv[s] * dinv[d];
    }
}

// out[node,f] = dinv[node]^2 * feat[node,f] + sum_e csr_wt[e]*feat[csr_src[e],f]
__global__ __launch_bounds__(128) void agg_kernel(const float* __restrict__ feat,
                                                  const int* __restrict__ row_ptr,
                                                  const int* __restrict__ csr_src,
                                                  const float* __restrict__ csr_wt,
                                                  const float* __restrict__ dinv,
                                                  float* __restrict__ out, int n) {
    int node = blockIdx.x;
    int f = threadIdx.x;
    float di = dinv[node];
    float acc = feat[(size_t)node * 128 + f] * di * di;   // self-loop
    int e0 = row_ptr[node], e1 = row_ptr[node + 1];
    int e = e0;
    for (; e + 4 <= e1; e += 4) {
        int s0 = csr_src[e],   s1 = csr_src[e+1], s2 = csr_src[e+2], s3 = csr_src[e+3];
        float w0 = csr_wt[e],  w1 = csr_wt[e+1],  w2 = csr_wt[e+2],  w3 = csr_wt[e+3];
        float v0 = feat[(size_t)s0 * 128 + f];
        float v1 = feat[(size_t)s1 * 128 + f];
        float v2 = feat[(size_t)s2 * 128 + f];
        float v3 = feat[(size_t)s3 * 128 + f];
        acc += v0 * w0 + v1 * w1 + v2 * w2 + v3 * w3;
    }
    for (; e < e1; ++e)
        acc += feat[(size_t)csr_src[e] * 128 + f] * csr_wt[e];
    out[(size_t)node * 128 + f] = acc;
}

// C[N, 128-col chunk] = X[N,128] @ W[128, ldw] + bias, optional relu.
__global__ __launch_bounds__(256) void gemm_rm(const float* __restrict__ X,
                                               const float* __restrict__ W,
                                               const float* __restrict__ bias,
                                               float* __restrict__ C,
                                               int N, int ldw, int do_relu) {
    __shared__ float Wl[128 * 128];  // 64 KB
    __shared__ float Xl[32 * 128];   // 16 KB
    int tx = threadIdx.x & 31;       // col group of 4 (covers 128 cols)
    int ty = threadIdx.x >> 5;       // 0..7 (row within group of 8)
    int colOff = blockIdx.y * 128;
    int row0 = blockIdx.x * 32;

    for (int i = threadIdx.x; i < 128 * 32; i += 256) {   // W chunk as float4
        int k = i >> 5, j4 = i & 31;
        ((float4*)Wl)[i] = *(const float4*)(W + (size_t)k * ldw + colOff + j4 * 4);
    }
    for (int i = threadIdx.x; i < 32 * 32; i += 256) {    // X tile as float4
        int r = i >> 5, k4 = i & 31;
        int row = row0 + r; if (row >= N) row = N - 1;
        ((float4*)Xl)[i] = *(const float4*)(X + (size_t)row * 128 + k4 * 4);
    }
    __syncthreads();

    float4 acc[4] = {};
    for (int k = 0; k < 128; ++k) {
        float4 w = ((const float4*)Wl)[k * 32 + tx];
#pragma unroll
        for (int i = 0; i < 4; ++i) {
            float xv = Xl[(ty + 8 * i) * 128 + k];
            acc[i].x += xv * w.x; acc[i].y += xv * w.y;
            acc[i].z += xv * w.z; acc[i].w += xv * w.w;
        }
    }
    float4 bb = *(const float4*)(bias + colOff + tx * 4);
#pragma unroll
    for (int i = 0; i < 4; ++i) {
        acc[i].x += bb.x; acc[i].y += bb.y; acc[i].z += bb.z; acc[i].w += bb.w;
        if (do_relu) {
            acc[i].x = acc[i].x > 0.f ? acc[i].x : 0.f;
            acc[i].y = acc[i].y > 0.f ? acc[i].y : 0.f;
            acc[i].z = acc[i].z > 0.f ? acc[i].z : 0.f;
            acc[i].w = acc[i].w > 0.f ? acc[i].w : 0.f;
        }
        int r = row0 + ty + 8 * i;
        if (r < N)
            *(float4*)(C + (size_t)r * ldw + colOff + tx * 4) = acc[i];
    }
}

// one 64-lane wave per query edge; load only the two selected heads (1 KB/edge)
__global__ __launch_bounds__(256) void query_kernel(const float* __restrict__ emb,
                                                    const int* __restrict__ qrow,
                                                    const int* __restrict__ qcol,
                                                    const int* __restrict__ y,
                                                    float* __restrict__ pred_i,
                                                    float* __restrict__ pred_j,
                                                    float* __restrict__ pred, int Q) {
    int wave = (int)((blockIdx.x * 256 + threadIdx.x) >> 6);
    int lane = threadIdx.x & 63;
    if (wave >= Q) return;
    int r = qrow[wave], c = qcol[wave];
    int yi = y[r], yj = y[c];   // same-address across wave -> broadcast
    const float* er = emb + (size_t)r * 512;
    const float* ec = emb + (size_t)c * 512;
    float pi = er[yi * 64 + lane] * ec[yi * 64 + lane];
    float pj = er[yj * 64 + lane] * ec[yj * 64 + lane];
#pragma unroll
    for (int off = 32; off >= 1; off >>= 1) {
        pi += __shfl_xor(pi, off, 64);
        pj += __shfl_xor(pj, off, 64);
    }
    if (lane == 0) {
        pred_i[wave] = pi;
        pred_j[wave] = pj;
        pred[wave]   = 0.5f * (pi + pj);
    }
}

extern "C" void kernel_launch(void* const* d_in, const int* in_sizes, int n_in,
                              void* d_out, int out_size, void* d_ws, size_t ws_size,
                              hipStream_t stream) {
    const float* x   = (const float*)d_in[0];
    const float* W1  = (const float*)d_in[1];
    const float* b1  = (const float*)d_in[2];
    const float* W2  = (const float*)d_in[3];
    const float* b2  = (const float*)d_in[4];
    const int* edge  = (const int*)d_in[5];
    const int* qedge = (const int*)d_in[6];
    const int* y     = (const int*)d_in[7];

    const int N = in_sizes[0] / 128;   // 100000
    const int E = in_sizes[5] / 2;     // 1600000
    const int Q = in_sizes[6] / 2;     // 400000

    float* out     = (float*)d_out;
    float* hiddens = out;                         // [N,128]
    float* emb     = out + (size_t)N * 128;       // [N,512]
    float* pred_i  = emb + (size_t)N * 512;       // [Q]
    float* pred_j  = pred_i + Q;                  // [Q]
    float* pred    = pred_j + Q;                  // [Q]

    // workspace carve (256B aligned)
    char* w = (char*)d_ws;
    auto alloc = [&](size_t bytes) { char* p = w; w += (bytes + 255) & ~(size_t)255; return p; };
    int*   cnt      = (int*)alloc((size_t)N * 4);
    int*   row_ptr  = (int*)alloc((size_t)(N + 1) * 4);
    int*   cursor   = (int*)alloc((size_t)N * 4);
    float* dinv     = (float*)alloc((size_t)N * 4);
    int*   csr_src  = (int*)alloc((size_t)E * 4);
    float* csr_wt   = (float*)alloc((size_t)E * 4);
    int*   blocksum = (int*)alloc(256 * 4);
    int*   blockoff = (int*)alloc(256 * 4);
    float* aggbuf   = (float*)alloc((size_t)N * 128 * 4);  // 51.2 MB, reused

    const int* esrc = edge;         const int* edst = edge + E;
    const int* qrow = qedge;        const int* qcol = qedge + Q;

    const int nb = (N + SCAN_SEG - 1) / SCAN_SEG;   // 196 <= 256

    hipMemsetAsync(cnt, 0, (size_t)N * 4, stream);
    count_kernel<<<dim3((E + 255) / 256), dim3(256), 0, stream>>>(edst, cnt, E);
    blocksum_kernel<<<dim3(nb), dim3(256), 0, stream>>>(cnt, blocksum, N);
    blockscan_kernel<<<dim3(1), dim3(256), 0, stream>>>(blocksum, blockoff, nb, row_ptr, N, E);
    csr_ptr_kernel<<<dim3(nb), dim3(256), 0, stream>>>(cnt, blockoff, row_ptr, cursor, dinv, N);
    fill_kernel<<<dim3((E + 255) / 256), dim3(256), 0, stream>>>(esrc, edst, cursor, dinv, csr_src, csr_wt, E);

    // layer 1: aggregate x, then GEMM with fused bias+relu
    agg_kernel<<<dim3(N), dim3(128), 0, stream>>>(x, row_ptr, csr_src, csr_wt, dinv, aggbuf, N);
    gemm_rm<<<dim3((N + 31) / 32, 1), dim3(256), 0, stream>>>(aggbuf, W1, b1, hiddens, N, 128, 1);

    // layer 2: aggregate hiddens, then GEMM with fused bias
    agg_kernel<<<dim3(N), dim3(128), 0, stream>>>(hiddens, row_ptr, csr_src, csr_wt, dinv, aggbuf, N);
    gemm_rm<<<dim3((N + 31) / 32, 4), dim3(256), 0, stream>>>(aggbuf, W2, b2, emb, N, 512, 0);

    query_kernel<<<dim3((Q + 3) / 4), dim3(256), 0, stream>>>(emb, qrow, qcol, y, pred_i, pred_j, pred, Q);
}